// Round 1
// baseline (45.610 us; speedup 1.0000x reference)
//
#include <hip/hip_runtime.h>
#include <math.h>

#define BB 32
#define LL 2048
#define DD 256
#define NC 16
#define SPLIT 16      // chunks per batch row
#define TPB 256       // 4 waves
#define TOK_PER_CHUNK (LL / SPLIT)   // 128
#define TOK_PER_WAVE  (TOK_PER_CHUNK / 4)  // 32

// ws layout (floats): emb_sum[BB*DD] | out_unnorm[BB*DD] | ysum[BB] | lens[BB]

__global__ __launch_bounds__(TPB) void kA_embsum(
    const int* __restrict__ idx, const float* __restrict__ mask,
    const float4* __restrict__ enc4,
    float* __restrict__ emb_sum, float* __restrict__ lens) {
  const int b     = blockIdx.x / SPLIT;
  const int chunk = blockIdx.x % SPLIT;
  const int wave  = threadIdx.x >> 6;
  const int lane  = threadIdx.x & 63;
  const int tid   = threadIdx.x;
  const int l0 = chunk * TOK_PER_CHUNK + wave * TOK_PER_WAVE;

  float4 acc = {0.f, 0.f, 0.f, 0.f};
  float lenacc = 0.f;
  for (int t = 0; t < TOK_PER_WAVE; ++t) {
    const int l = l0 + t;
    const int id = idx[b * LL + l];
    const float m = mask[b * LL + l];
    const float4 v = enc4[(size_t)id * (DD / 4) + lane];
    acc.x += v.x * m; acc.y += v.y * m; acc.z += v.z * m; acc.w += v.w * m;
    lenacc += m;
  }

  __shared__ float lds[4][DD];
  __shared__ float llds[4];
  lds[wave][lane * 4 + 0] = acc.x;
  lds[wave][lane * 4 + 1] = acc.y;
  lds[wave][lane * 4 + 2] = acc.z;
  lds[wave][lane * 4 + 3] = acc.w;
  if (lane == 0) llds[wave] = lenacc;   // lenacc identical across lanes of a wave
  __syncthreads();

  const float s = lds[0][tid] + lds[1][tid] + lds[2][tid] + lds[3][tid];
  atomicAdd(&emb_sum[b * DD + tid], s);
  if (tid == 0) atomicAdd(&lens[b], llds[0] + llds[1] + llds[2] + llds[3]);
}

__global__ __launch_bounds__(TPB) void kB_scores(
    const int* __restrict__ idx, const float* __restrict__ mask,
    const float4* __restrict__ enc4, const float* __restrict__ emb_sum,
    float* __restrict__ out_unnorm, float* __restrict__ ysum) {
  const int b     = blockIdx.x / SPLIT;
  const int chunk = blockIdx.x % SPLIT;
  const int wave  = threadIdx.x >> 6;
  const int lane  = threadIdx.x & 63;
  const int tid   = threadIdx.x;
  const int l0 = chunk * TOK_PER_CHUNK + wave * TOK_PER_WAVE;

  const float4 es = reinterpret_cast<const float4*>(emb_sum)[b * (DD / 4) + lane];

  float4 acc = {0.f, 0.f, 0.f, 0.f};
  float ys = 0.f;
  for (int t = 0; t < TOK_PER_WAVE; ++t) {
    const int l = l0 + t;
    const int id = idx[b * LL + l];
    const float m = mask[b * LL + l];
    const float4 v = enc4[(size_t)id * (DD / 4) + lane];
    float d = v.x * es.x + v.y * es.y + v.z * es.z + v.w * es.w;
    // 64-lane butterfly reduce
    #pragma unroll
    for (int off = 32; off > 0; off >>= 1) d += __shfl_xor(d, off);
    const float score = d * m;          // scores = mask * dot(enc_row, emb_sum)
    const float y = expf(score) * m;    // y = exp(scores) * mask
    const float ym = y * m;             // weight on enc row: attn_num * mask
    acc.x += ym * v.x; acc.y += ym * v.y; acc.z += ym * v.z; acc.w += ym * v.w;
    ys += y;                            // identical across lanes
  }

  __shared__ float lds[4][DD];
  __shared__ float ylds[4];
  lds[wave][lane * 4 + 0] = acc.x;
  lds[wave][lane * 4 + 1] = acc.y;
  lds[wave][lane * 4 + 2] = acc.z;
  lds[wave][lane * 4 + 3] = acc.w;
  if (lane == 0) ylds[wave] = ys;
  __syncthreads();

  const float s = lds[0][tid] + lds[1][tid] + lds[2][tid] + lds[3][tid];
  atomicAdd(&out_unnorm[b * DD + tid], s);
  if (tid == 0) atomicAdd(&ysum[b], ylds[0] + ylds[1] + ylds[2] + ylds[3]);
}

__global__ __launch_bounds__(TPB) void kC_head(
    const float* __restrict__ emb_sum, const float* __restrict__ out_unnorm,
    const float* __restrict__ ysum, const float* __restrict__ lens,
    const float* __restrict__ dec_w, float* __restrict__ out) {
  const int b = blockIdx.x;
  const int tid = threadIdx.x;
  __shared__ float vec[DD];
  vec[tid] = out_unnorm[b * DD + tid] / ysum[b] + emb_sum[b * DD + tid] / lens[b];
  __syncthreads();
  if (tid < NC) {
    float s = 0.f;
    for (int d2 = 0; d2 < DD; ++d2) s += vec[d2] * dec_w[tid * DD + d2];
    out[b * NC + tid] = s;
  }
}

extern "C" void kernel_launch(void* const* d_in, const int* in_sizes, int n_in,
                              void* d_out, int out_size, void* d_ws, size_t ws_size,
                              hipStream_t stream) {
  const int*   idx   = (const int*)d_in[0];
  const float* mask  = (const float*)d_in[1];
  const float* enc_w = (const float*)d_in[2];
  const float* dec_w = (const float*)d_in[3];
  float* out = (float*)d_out;

  float* ws = (float*)d_ws;
  float* emb_sum    = ws;                       // BB*DD
  float* out_unnorm = ws + BB * DD;             // BB*DD
  float* ysum       = ws + 2 * BB * DD;         // BB
  float* lens       = ws + 2 * BB * DD + BB;    // BB

  const size_t zero_bytes = (2 * BB * DD + 2 * BB) * sizeof(float);
  hipMemsetAsync(d_ws, 0, zero_bytes, stream);

  const dim3 grid(BB * SPLIT), block(TPB);
  hipLaunchKernelGGL(kA_embsum, grid, block, 0, stream,
                     idx, mask, (const float4*)enc_w, emb_sum, lens);
  hipLaunchKernelGGL(kB_scores, grid, block, 0, stream,
                     idx, mask, (const float4*)enc_w, emb_sum, out_unnorm, ysum);
  hipLaunchKernelGGL(kC_head, dim3(BB), block, 0, stream,
                     emb_sum, out_unnorm, ysum, lens, dec_w, out);
}

// Round 2
// 45.515 us; speedup vs baseline: 1.0021x; 1.0021x over previous
//
#include <hip/hip_runtime.h>
#include <math.h>

#define BB 32
#define LL 2048
#define DD 256
#define NC 16
#define SPLIT 16      // chunks per batch row
#define TPB 256       // 4 waves
#define TOK_PER_CHUNK (LL / SPLIT)   // 128
#define TOK_PER_WAVE  (TOK_PER_CHUNK / 4)  // 32

// ws layout (floats): emb_sum[BB*DD] | out_unnorm[BB*DD] | ysum[BB] | lens[BB]
#define WS_FLOATS (2 * BB * DD + 2 * BB)

__global__ __launch_bounds__(TPB) void kZero(float* __restrict__ ws) {
  const int i = blockIdx.x * TPB + threadIdx.x;
  if (i < WS_FLOATS) ws[i] = 0.f;
}

__global__ __launch_bounds__(TPB) void kA_embsum(
    const int* __restrict__ idx, const float* __restrict__ mask,
    const float4* __restrict__ enc4,
    float* __restrict__ emb_sum, float* __restrict__ lens) {
  const int b     = blockIdx.x / SPLIT;
  const int chunk = blockIdx.x % SPLIT;
  const int wave  = threadIdx.x >> 6;
  const int lane  = threadIdx.x & 63;
  const int tid   = threadIdx.x;
  const int l0 = chunk * TOK_PER_CHUNK + wave * TOK_PER_WAVE;

  float4 acc = {0.f, 0.f, 0.f, 0.f};
  float lenacc = 0.f;
  for (int t = 0; t < TOK_PER_WAVE; ++t) {
    const int l = l0 + t;
    const int id = idx[b * LL + l];
    const float m = mask[b * LL + l];
    const float4 v = enc4[(size_t)id * (DD / 4) + lane];
    acc.x += v.x * m; acc.y += v.y * m; acc.z += v.z * m; acc.w += v.w * m;
    lenacc += m;
  }

  __shared__ float lds[4][DD];
  __shared__ float llds[4];
  lds[wave][lane * 4 + 0] = acc.x;
  lds[wave][lane * 4 + 1] = acc.y;
  lds[wave][lane * 4 + 2] = acc.z;
  lds[wave][lane * 4 + 3] = acc.w;
  if (lane == 0) llds[wave] = lenacc;   // lenacc identical across lanes of a wave
  __syncthreads();

  const float s = lds[0][tid] + lds[1][tid] + lds[2][tid] + lds[3][tid];
  atomicAdd(&emb_sum[b * DD + tid], s);
  if (tid == 0) atomicAdd(&lens[b], llds[0] + llds[1] + llds[2] + llds[3]);
}

__global__ __launch_bounds__(TPB) void kB_scores(
    const int* __restrict__ idx, const float* __restrict__ mask,
    const float4* __restrict__ enc4, const float* __restrict__ emb_sum,
    float* __restrict__ out_unnorm, float* __restrict__ ysum) {
  const int b     = blockIdx.x / SPLIT;
  const int chunk = blockIdx.x % SPLIT;
  const int wave  = threadIdx.x >> 6;
  const int lane  = threadIdx.x & 63;
  const int tid   = threadIdx.x;
  const int l0 = chunk * TOK_PER_CHUNK + wave * TOK_PER_WAVE;

  const float4 es = reinterpret_cast<const float4*>(emb_sum)[b * (DD / 4) + lane];

  float4 acc = {0.f, 0.f, 0.f, 0.f};
  float ys = 0.f;
  for (int t = 0; t < TOK_PER_WAVE; ++t) {
    const int l = l0 + t;
    const int id = idx[b * LL + l];
    const float m = mask[b * LL + l];
    const float4 v = enc4[(size_t)id * (DD / 4) + lane];
    float d = v.x * es.x + v.y * es.y + v.z * es.z + v.w * es.w;
    // 64-lane butterfly reduce
    #pragma unroll
    for (int off = 32; off > 0; off >>= 1) d += __shfl_xor(d, off);
    const float score = d * m;          // scores = mask * dot(enc_row, emb_sum)
    const float y = expf(score) * m;    // y = exp(scores) * mask
    const float ym = y * m;             // weight on enc row: attn_num * mask
    acc.x += ym * v.x; acc.y += ym * v.y; acc.z += ym * v.z; acc.w += ym * v.w;
    ys += y;                            // identical across lanes
  }

  __shared__ float lds[4][DD];
  __shared__ float ylds[4];
  lds[wave][lane * 4 + 0] = acc.x;
  lds[wave][lane * 4 + 1] = acc.y;
  lds[wave][lane * 4 + 2] = acc.z;
  lds[wave][lane * 4 + 3] = acc.w;
  if (lane == 0) ylds[wave] = ys;
  __syncthreads();

  const float s = lds[0][tid] + lds[1][tid] + lds[2][tid] + lds[3][tid];
  atomicAdd(&out_unnorm[b * DD + tid], s);
  if (tid == 0) atomicAdd(&ysum[b], ylds[0] + ylds[1] + ylds[2] + ylds[3]);
}

__global__ __launch_bounds__(TPB) void kC_head(
    const float* __restrict__ emb_sum, const float* __restrict__ out_unnorm,
    const float* __restrict__ ysum, const float* __restrict__ lens,
    const float* __restrict__ dec_w, float* __restrict__ out) {
  const int b = blockIdx.x;
  const int tid = threadIdx.x;
  __shared__ float vec[DD];
  vec[tid] = out_unnorm[b * DD + tid] / ysum[b] + emb_sum[b * DD + tid] / lens[b];
  __syncthreads();
  if (tid < NC) {
    float s = 0.f;
    for (int d2 = 0; d2 < DD; ++d2) s += vec[d2] * dec_w[tid * DD + d2];
    out[b * NC + tid] = s;
  }
}

extern "C" void kernel_launch(void* const* d_in, const int* in_sizes, int n_in,
                              void* d_out, int out_size, void* d_ws, size_t ws_size,
                              hipStream_t stream) {
  const int*   idx   = (const int*)d_in[0];
  const float* mask  = (const float*)d_in[1];
  const float* enc_w = (const float*)d_in[2];
  const float* dec_w = (const float*)d_in[3];
  float* out = (float*)d_out;

  float* ws = (float*)d_ws;
  float* emb_sum    = ws;                       // BB*DD
  float* out_unnorm = ws + BB * DD;             // BB*DD
  float* ysum       = ws + 2 * BB * DD;         // BB
  float* lens       = ws + 2 * BB * DD + BB;    // BB

  const dim3 block(TPB);
  hipLaunchKernelGGL(kZero, dim3((WS_FLOATS + TPB - 1) / TPB), block, 0, stream, ws);

  const dim3 grid(BB * SPLIT);
  hipLaunchKernelGGL(kA_embsum, grid, block, 0, stream,
                     idx, mask, (const float4*)enc_w, emb_sum, lens);
  hipLaunchKernelGGL(kB_scores, grid, block, 0, stream,
                     idx, mask, (const float4*)enc_w, emb_sum, out_unnorm, ysum);
  hipLaunchKernelGGL(kC_head, dim3(BB), block, 0, stream,
                     emb_sum, out_unnorm, ysum, lens, dec_w, out);
}